// Round 10
// baseline (327.800 us; speedup 1.0000x reference)
//
#include <hip/hip_runtime.h>
#include <hip/hip_bf16.h>

#define B_ 4
#define H_ 16
#define S_ 2048
#define D_ 64
#define QBLK 128
#define NQB 16        // S_/QBLK
#define THREADS 512

typedef float  f32x4  __attribute__((ext_vector_type(4)));
typedef short  bf16x8 __attribute__((ext_vector_type(8)));
typedef unsigned uint2v __attribute__((ext_vector_type(2)));

#define LOG2E_O8  0.18033688011112042f   // log2(e)/8
#define M20LOG2E -28.853900817779268f    // -20*log2(e)

// packed f32x2 -> bf16x2 (RNE), single VOP3 instr
__device__ __forceinline__ unsigned cvt_pk(float lo, float hi) {
    unsigned r;
    asm("v_cvt_pk_bf16_f32 %0, %1, %2" : "=v"(r) : "v"(lo), "v"(hi));
    return r;
}

// plain (L2-coalescing) wide store — NT bypassed L2 write-combining; the rocclr
// fill proves the L2 path sustains 6.5 TB/s for streaming writes.
__device__ __forceinline__ void st4(float* p, f32x4 v) {
    *(f32x4*)p = v;
}

// LDS-only barrier (no vmcnt drain): in-flight global stores/loads float across.
__device__ __forceinline__ void bar_lds() {
    asm volatile("s_waitcnt lgkmcnt(0)\n\ts_barrier" ::: "memory");
}

// swizzled 16B-slot index for a [rows][64 bf16] LDS tile (8 slots/row)
__device__ __forceinline__ int swz(int row, int s8) {
    return row * 8 + (s8 ^ ((row & 7) ^ ((row >> 3) & 7)));
}

__device__ __forceinline__ bf16x8 frag_ld(const short* lds, int row, int s8) {
    return *(const bf16x8*)((const char*)lds + 16 * swz(row, s8));
}

// ---- K-tile (64x64 f32) reg staging: 2 f32x4 per thread (512 threads) ----
__device__ __forceinline__ void kload(f32x4 (&r)[2], const float* __restrict__ g, int t) {
    r[0] = *(const f32x4*)(g + 4 * t);
    r[1] = *(const f32x4*)(g + 4 * (t + THREADS));
}
__device__ __forceinline__ void kwrite(short* lds, const f32x4 (&r)[2], int t) {
#pragma unroll
    for (int i = 0; i < 2; ++i) {
        int f = t + i * THREADS;
        int row = f >> 4, c4 = f & 15;
        uint2v h;
        h.x = cvt_pk(r[i].x, r[i].y);
        h.y = cvt_pk(r[i].z, r[i].w);
        *(uint2v*)((char*)lds + 16 * swz(row, c4 >> 1) + (c4 & 1) * 8) = h;
    }
}
// ---- V-tile (64x64) reg staging for TRANSPOSED store ----
__device__ __forceinline__ void vload(f32x4 (&r)[2], const float* __restrict__ g, int t) {
    int k0 = (t >> 4) * 2, d0 = (t & 15) * 4;
    r[0] = *(const f32x4*)(g + k0 * 64 + d0);
    r[1] = *(const f32x4*)(g + (k0 + 1) * 64 + d0);
}
__device__ __forceinline__ void vtwrite(short* lds, const f32x4 (&r)[2], int t) {
    int k0 = (t >> 4) * 2, d0 = (t & 15) * 4;
#pragma unroll
    for (int j = 0; j < 4; ++j) {
        unsigned pk = cvt_pk(r[0][j], r[1][j]);    // (k0 low, k0+1 high)
        int row = d0 + j;                          // d -> Vt row
        *(unsigned*)((char*)lds + 16 * swz(row, k0 >> 3) + (k0 & 7) * 2) = pk;
    }
}

__global__ __launch_bounds__(THREADS, 4)   // 4 waves/EU = 16 waves/CU = 2 blocks/CU
void attn_kernel(const float* __restrict__ Q, const float* __restrict__ K,
                 const float* __restrict__ V, float* __restrict__ Out) {
    const int t    = threadIdx.x;
    const int lane = t & 63;
    const int w    = t >> 6;        // wave 0..7
    const int l15  = lane & 15;
    const int l4   = lane >> 4;     // 0..3

    // XCD-chunked swizzle + phase-staggered qbi (bijective per head)
    const int bid = blockIdx.x;
    const int u   = bid >> 3;                         // 0..127 within XCD
    const int qbi = (NQB - 1) - ((u + 4 * (u >> 5)) & (NQB - 1));
    const int bh  = (bid & 7) * 8 + (u >> 4);
    const int q0  = qbi * QBLK;

    const float* Qg = Q + ((size_t)bh * S_ + q0) * D_;
    const float* Kg = K + (size_t)bh * S_ * D_;
    const float* Vg = V + (size_t)bh * S_ * D_;
    float* Og = Out + ((size_t)bh * S_ + q0) * D_;
    float* Wg = Out + (size_t)B_ * H_ * S_ * D_ + ((size_t)bh * S_ + q0) * (size_t)S_;

    __shared__ char pool[40960];
    short* lkb = (short*)pool;                        // K dbuf 2x8KB
    short* lv  = (short*)(pool + 16384);              // Vt single buf 8KB
    short* lp  = (short*)(pool + 24576) + w * 1024;   // per-wave P tile 2KB

    // -------- zero-fill dead region --------
    {
        f32x4 z = {0.f, 0.f, 0.f, 0.f};
        for (int row = 0; row < QBLK; ++row) {
            int c0 = q0 + (row & ~63) + 64;
            float* p = Wg + (size_t)row * S_;
            for (int c = c0 + 4 * t; c < S_; c += 4 * THREADS)
                st4(p + c, z);
        }
    }

    // -------- Q fragments straight from global (no LDS stage) --------
    bf16x8 qa0, qa1;
    {
        const float* qrow = Qg + (size_t)(16 * w + l15) * D_;
        f32x4 a0 = *(const f32x4*)(qrow + 8 * l4);
        f32x4 a1 = *(const f32x4*)(qrow + 8 * l4 + 4);
        f32x4 b0 = *(const f32x4*)(qrow + 32 + 8 * l4);
        f32x4 b1 = *(const f32x4*)(qrow + 32 + 8 * l4 + 4);
        union { bf16x8 v; unsigned u[4]; } q0u, q1u;
        q0u.u[0] = cvt_pk(a0.x, a0.y); q0u.u[1] = cvt_pk(a0.z, a0.w);
        q0u.u[2] = cvt_pk(a1.x, a1.y); q0u.u[3] = cvt_pk(a1.z, a1.w);
        q1u.u[0] = cvt_pk(b0.x, b0.y); q1u.u[1] = cvt_pk(b0.z, b0.w);
        q1u.u[2] = cvt_pk(b1.x, b1.y); q1u.u[3] = cvt_pk(b1.z, b1.w);
        qa0 = q0u.v; qa1 = q1u.v;
    }

    const int ktmax  = (q0 + QBLK - 1) >> 6;       // inclusive, >= 1
    const int qwbase = q0 + 16 * w;                // wave's first q row
    const int qg     = qwbase + l15;               // this lane's q row (S^T layout)

    // ---------------- sweep 1: row sums (fixed max = 20) ----------------------
    // swapped QK^T: mfma(K,Q) -> lane holds S[q=l15][k=kgb+4*l4+r]
    f32x4 kreg[2];
    kload(kreg, Kg, t);
    kwrite(lkb, kreg, t);
    kload(kreg, Kg + 4096, t);
    bar_lds();

    f32x4 lsum4 = {0.f, 0.f, 0.f, 0.f};           // 4 independent chains
    for (int kt = 0; kt <= ktmax; ++kt) {
        const short* lk = lkb + (kt & 1) * 4096;
#pragma unroll
        for (int kc = 0; kc < 4; ++kc) {
            int kgb = kt * 64 + 16 * kc;
            if (kgb > qwbase) break;            // wave-uniform (dead)
            bf16x8 kb0 = frag_ld(lk, 16 * kc + l15, 0 + l4);
            bf16x8 kb1 = frag_ld(lk, 16 * kc + l15, 4 + l4);
            f32x4 acc = {0.f, 0.f, 0.f, 0.f};
            acc = __builtin_amdgcn_mfma_f32_16x16x32_bf16(kb0, qa0, acc, 0, 0, 0);
            acc = __builtin_amdgcn_mfma_f32_16x16x32_bf16(kb1, qa1, acc, 0, 0, 0);
            if (kgb != qwbase) {                // interior: all 16 live, no mask
#pragma unroll
                for (int r = 0; r < 4; ++r)
                    lsum4[r] += exp2f(fmaf(acc[r], LOG2E_O8, M20LOG2E));
            } else {                            // diagonal-partial sub-tile
#pragma unroll
                for (int r = 0; r < 4; ++r) {
                    int kg = kgb + 4 * l4 + r;
                    if (kg <= qg) lsum4[r] += exp2f(fmaf(acc[r], LOG2E_O8, M20LOG2E));
                }
            }
        }
        if (kt < ktmax) {
            kwrite(lkb + ((kt + 1) & 1) * 4096, kreg, t);
            if (kt + 1 < ktmax) kload(kreg, Kg + (size_t)(kt + 2) * 4096, t);
        }
        bar_lds();
    }
    float lsum = (lsum4[0] + lsum4[1]) + (lsum4[2] + lsum4[3]);
    lsum += __shfl_xor(lsum, 16);
    lsum += __shfl_xor(lsum, 32);
    const float c2 = M20LOG2E - __log2f(lsum);   // exp2(fma(s,LOG2E_O8,c2)) = normalized w

    // ------------- sweep 2: weights write + PV ----------------------
    f32x4 oacc[4];
#pragma unroll
    for (int dt = 0; dt < 4; ++dt) oacc[dt] = (f32x4){0.f, 0.f, 0.f, 0.f};

    f32x4 vreg[2];
    kload(kreg, Kg, t);
    vload(vreg, Vg, t);
    kwrite(lkb, kreg, t);          // all waves passed sweep1's final barrier
    vtwrite(lv, vreg, t);          // V0
    kload(kreg, Kg + 4096, t);
    vload(vreg, Vg + 4096, t);
    bar_lds();

    for (int kt = 0; kt <= ktmax; ++kt) {
        const short* lk = lkb + (kt & 1) * 4096;
        const bool blive = (kt * 64 <= qwbase);    // wave-uniform: tile has live cols

        if (blive) {
            // ---- compute all 4 kc sub-tiles; P -> per-wave LDS (bf16) ----
#pragma unroll
            for (int kc = 0; kc < 4; ++kc) {
                int kgb = kt * 64 + 16 * kc;
                bool live = (kgb <= qwbase);       // wave-uniform
                f32x4 wv;
                if (live) {
                    bf16x8 kb0 = frag_ld(lk, 16 * kc + l15, 0 + l4);
                    bf16x8 kb1 = frag_ld(lk, 16 * kc + l15, 4 + l4);
                    f32x4 acc = {0.f, 0.f, 0.f, 0.f};
                    acc = __builtin_amdgcn_mfma_f32_16x16x32_bf16(kb0, qa0, acc, 0, 0, 0);
                    acc = __builtin_amdgcn_mfma_f32_16x16x32_bf16(kb1, qa1, acc, 0, 0, 0);
                    if (kgb != qwbase) {           // interior: no per-element mask
#pragma unroll
                        for (int r = 0; r < 4; ++r)
                            wv[r] = exp2f(fmaf(acc[r], LOG2E_O8, c2));
                    } else {
#pragma unroll
                        for (int r = 0; r < 4; ++r) {
                            int kg = kgb + 4 * l4 + r;
                            wv[r] = (kg <= qg) ? exp2f(fmaf(acc[r], LOG2E_O8, c2)) : 0.0f;
                        }
                    }
                } else {
                    wv = (f32x4){0.f, 0.f, 0.f, 0.f};
                }
                uint2v pk;
                pk.x = cvt_pk(wv[0], wv[1]);
                pk.y = cvt_pk(wv[2], wv[3]);
                int s8 = 2 * kc + (l4 >> 1);
                *(uint2v*)((char*)lp + 16 * swz(l15, s8) + (l4 & 1) * 8) = pk;
            }
            // ---- W store: LDS-transposed, 16 lanes per row -> 256B runs ----
#pragma unroll
            for (int j = 0; j < 4; ++j) {
                int rr = j * 4 + l4;               // tile row 0..15
                uint2v pk = *(const uint2v*)((char*)lp + 16 * swz(rr, l15 >> 1) + (l15 & 1) * 8);
                f32x4 wf;
                wf.x = __uint_as_float(pk.x << 16);
                wf.y = __uint_as_float(pk.x & 0xffff0000u);
                wf.z = __uint_as_float(pk.y << 16);
                wf.w = __uint_as_float(pk.y & 0xffff0000u);
                st4(Wg + (size_t)(16 * w + rr) * S_ + kt * 64 + 4 * l15, wf);
            }
        }

        // stage next K while PV runs (lkb[nxt] safe: sealed by prev bar pair)
        if (kt < ktmax) {
            kwrite(lkb + ((kt + 1) & 1) * 4096, kreg, t);
            if (kt + 1 < ktmax) kload(kreg, Kg + (size_t)(kt + 2) * 4096, t);
        }

        if (blive) {
            // ---- PV: O[16q x 64d] += P(16x64) * Vt (single buf, V=kt) ----
#pragma unroll
            for (int kchunk = 0; kchunk < 2; ++kchunk) {
                bf16x8 pa = frag_ld(lp, l15, kchunk * 4 + l4);
#pragma unroll
                for (int dt = 0; dt < 4; ++dt) {
                    bf16x8 vb = frag_ld(lv, 16 * dt + l15, kchunk * 4 + l4);
                    oacc[dt] = __builtin_amdgcn_mfma_f32_16x16x32_bf16(pa, vb, oacc[dt], 0, 0, 0);
                }
            }
        }
        bar_lds();                                 // all PV(kt) reads of lv done
        if (kt < ktmax) {
            vtwrite(lv, vreg, t);                  // V(kt+1) into single buf
            if (kt + 1 < ktmax) vload(vreg, Vg + (size_t)(kt + 2) * 4096, t);
        }
        bar_lds();                                 // vtwrite complete before PV(kt+1)
    }

    // -------- write O --------
#pragma unroll
    for (int dt = 0; dt < 4; ++dt)
#pragma unroll
        for (int r = 0; r < 4; ++r)
            Og[(size_t)(16 * w + 4 * l4 + r) * D_ + 16 * dt + l15] = oacc[dt][r];
}

extern "C" void kernel_launch(void* const* d_in, const int* in_sizes, int n_in,
                              void* d_out, int out_size, void* d_ws, size_t ws_size,
                              hipStream_t stream) {
    const float* q = (const float*)d_in[0];
    const float* k = (const float*)d_in[1];
    const float* v = (const float*)d_in[2];
    float* out = (float*)d_out;
    attn_kernel<<<dim3(B_ * H_ * NQB), dim3(THREADS), 0, stream>>>(q, k, v, out);
}

// Round 11
// 241.424 us; speedup vs baseline: 1.3578x; 1.3578x over previous
//
#include <hip/hip_runtime.h>
#include <hip/hip_bf16.h>

#define B_ 4
#define H_ 16
#define S_ 2048
#define D_ 64
#define THREADS 512

typedef float  f32x4  __attribute__((ext_vector_type(4)));
typedef short  bf16x8 __attribute__((ext_vector_type(8)));
typedef unsigned uint2v __attribute__((ext_vector_type(2)));

#define LOG2E_O8  0.18033688011112042f   // log2(e)/8
#define M20LOG2E -28.853900817779268f    // -20*log2(e)

// packed f32x2 -> bf16x2 (RNE), single VOP3 instr
__device__ __forceinline__ unsigned cvt_pk(float lo, float hi) {
    unsigned r;
    asm("v_cvt_pk_bf16_f32 %0, %1, %2" : "=v"(r) : "v"(lo), "v"(hi));
    return r;
}

__device__ __forceinline__ void nt_store4(float* p, f32x4 v) {
    __builtin_nontemporal_store(v, (f32x4*)p);
}

// LDS-only barrier (no vmcnt drain): in-flight global stores/loads float across.
__device__ __forceinline__ void bar_lds() {
    asm volatile("s_waitcnt lgkmcnt(0)\n\ts_barrier" ::: "memory");
}

// swizzled 16B-slot index for a [rows][64 bf16] LDS tile (8 slots/row)
__device__ __forceinline__ int swz(int row, int s8) {
    return row * 8 + (s8 ^ ((row & 7) ^ ((row >> 3) & 7)));
}

__device__ __forceinline__ bf16x8 frag_ld(const short* lds, int row, int s8) {
    return *(const bf16x8*)((const char*)lds + 16 * swz(row, s8));
}

// ---- K-tile (64x64 f32) reg staging: 2 f32x4 per thread (512 threads) ----
__device__ __forceinline__ void kload(f32x4 (&r)[2], const float* __restrict__ g, int t) {
    r[0] = *(const f32x4*)(g + 4 * t);
    r[1] = *(const f32x4*)(g + 4 * (t + THREADS));
}
__device__ __forceinline__ void kwrite(short* lds, const f32x4 (&r)[2], int t) {
#pragma unroll
    for (int i = 0; i < 2; ++i) {
        int f = t + i * THREADS;
        int row = f >> 4, c4 = f & 15;
        uint2v h;
        h.x = cvt_pk(r[i].x, r[i].y);
        h.y = cvt_pk(r[i].z, r[i].w);
        *(uint2v*)((char*)lds + 16 * swz(row, c4 >> 1) + (c4 & 1) * 8) = h;
    }
}
// ---- V-tile (64x64) reg staging for TRANSPOSED store ----
__device__ __forceinline__ void vload(f32x4 (&r)[2], const float* __restrict__ g, int t) {
    int k0 = (t >> 4) * 2, d0 = (t & 15) * 4;
    r[0] = *(const f32x4*)(g + k0 * 64 + d0);
    r[1] = *(const f32x4*)(g + (k0 + 1) * 64 + d0);
}
__device__ __forceinline__ void vtwrite(short* lds, const f32x4 (&r)[2], int t) {
    int k0 = (t >> 4) * 2, d0 = (t & 15) * 4;
#pragma unroll
    for (int j = 0; j < 4; ++j) {
        unsigned pk = cvt_pk(r[0][j], r[1][j]);    // (k0 low, k0+1 high)
        int row = d0 + j;                          // d -> Vt row
        *(unsigned*)((char*)lds + 16 * swz(row, k0 >> 3) + (k0 & 7) * 2) = pk;
    }
}

__global__ __launch_bounds__(THREADS)
void attn_kernel(const float* __restrict__ Q, const float* __restrict__ K,
                 const float* __restrict__ V, float* __restrict__ Out) {
    const int t    = threadIdx.x;
    const int lane = t & 63;
    const int w    = t >> 6;        // wave 0..7
    const int wg   = w & 3;         // wave within 4-wave group
    const int grp  = w >> 2;        // 0 -> subtile a, 1 -> subtile b
    const int l15  = lane & 15;
    const int l4   = lane >> 4;     // 0..3

    // XCD-chunked head mapping; block = complementary 64-row subtile pair (a, 31-a)
    const int bid = blockIdx.x;
    const int u   = bid >> 3;                 // 0..127 within XCD
    const int bh  = (bid & 7) * 8 + (u >> 4); // head (8 per XCD)
    const int a   = u & 15;                   // pair index
    const int b   = 31 - a;
    const int q0  = (grp ? b : a) * 64;       // this wave-group's subtile base

    const float* Kg = K + (size_t)bh * S_ * D_;
    const float* Vg = V + (size_t)bh * S_ * D_;
    float* Wh = Out + (size_t)B_ * H_ * S_ * D_ + (size_t)bh * S_ * (size_t)S_;
    float* Oh = Out + (size_t)bh * S_ * D_;

    __shared__ char pool[40960];
    short* lkb = (short*)pool;                        // K dbuf 2x8KB
    short* lv  = (short*)(pool + 16384);              // Vt single buf 8KB
    short* lp  = (short*)(pool + 24576) + w * 1024;   // per-wave P tile 2KB

    // -------- Q fragments straight from global --------
    bf16x8 qa0, qa1;
    {
        const float* qrow = Q + ((size_t)bh * S_ + q0 + 16 * wg + l15) * D_;
        f32x4 a0 = *(const f32x4*)(qrow + 8 * l4);
        f32x4 a1 = *(const f32x4*)(qrow + 8 * l4 + 4);
        f32x4 b0 = *(const f32x4*)(qrow + 32 + 8 * l4);
        f32x4 b1 = *(const f32x4*)(qrow + 32 + 8 * l4 + 4);
        union { bf16x8 v; unsigned u[4]; } q0u, q1u;
        q0u.u[0] = cvt_pk(a0.x, a0.y); q0u.u[1] = cvt_pk(a0.z, a0.w);
        q0u.u[2] = cvt_pk(a1.x, a1.y); q0u.u[3] = cvt_pk(a1.z, a1.w);
        q1u.u[0] = cvt_pk(b0.x, b0.y); q1u.u[1] = cvt_pk(b0.z, b0.w);
        q1u.u[2] = cvt_pk(b1.x, b1.y); q1u.u[3] = cvt_pk(b1.z, b1.w);
        qa0 = q0u.v; qa1 = q1u.v;
    }

    const int qwbase = q0 + 16 * wg;               // wave's first q row
    const int qg     = qwbase + l15;               // lane's q row (S^T layout)

    // ---------------- sweep 1: row sums + PACED zero-fill ----------------------
    // swapped QK^T: mfma(K,Q) -> lane holds S[q=l15][k=kgb+4*l4+r]
    f32x4 kreg[2];
    kload(kreg, Kg, t);
    kwrite(lkb, kreg, t);
    kload(kreg, Kg + 4096, t);
    bar_lds();

    // fill state: 31 dead 64x64 tiles (const per block) as 62 half-tiles
    int fcur = 0;
    const int fquota = (62 + b) / (b + 1);        // ceil(62/(b+1)) in {2,3,4}
    const f32x4 z4 = {0.f, 0.f, 0.f, 0.f};
    const int frow = t >> 4, fcol = 4 * (t & 15);

    f32x4 lsum4 = {0.f, 0.f, 0.f, 0.f};           // 4 independent chains
    for (int kt = 0; kt <= b; ++kt) {
        const short* lk = lkb + (kt & 1) * 4096;
        if (kt * 64 <= qwbase) {
#pragma unroll
            for (int kc = 0; kc < 4; ++kc) {
                int kgb = kt * 64 + 16 * kc;
                if (kgb > qwbase) break;            // wave-uniform (dead)
                bf16x8 kb0 = frag_ld(lk, 16 * kc + l15, 0 + l4);
                bf16x8 kb1 = frag_ld(lk, 16 * kc + l15, 4 + l4);
                f32x4 acc = {0.f, 0.f, 0.f, 0.f};
                acc = __builtin_amdgcn_mfma_f32_16x16x32_bf16(kb0, qa0, acc, 0, 0, 0);
                acc = __builtin_amdgcn_mfma_f32_16x16x32_bf16(kb1, qa1, acc, 0, 0, 0);
                if (kgb != qwbase) {                // interior: all 16 live
#pragma unroll
                    for (int r = 0; r < 4; ++r)
                        lsum4[r] += exp2f(fmaf(acc[r], LOG2E_O8, M20LOG2E));
                } else {                            // diagonal-partial sub-tile
#pragma unroll
                    for (int r = 0; r < 4; ++r) {
                        int kg = kgb + 4 * l4 + r;
                        if (kg <= qg) lsum4[r] += exp2f(fmaf(acc[r], LOG2E_O8, M20LOG2E));
                    }
                }
            }
        }
        // paced zero-fill: fquota half-tiles (8KB each) per iteration
        for (int f = 0; f < fquota; ++f) {
            if (fcur >= 62) break;
            int zt = fcur >> 1, half = fcur & 1;
            int rowb, ktile;
            if (zt < b) { rowb = 64 * a; ktile = a + 1 + zt; }   // tile-a dead cols
            else        { rowb = 64 * b; ktile = zt + 1; }       // tile-b dead cols
            nt_store4(Wh + (size_t)(rowb + 32 * half + frow) * S_ + 64 * ktile + fcol, z4);
            ++fcur;
        }
        if (kt < b) {
            kwrite(lkb + ((kt + 1) & 1) * 4096, kreg, t);
            if (kt + 1 < b) kload(kreg, Kg + (size_t)(kt + 2) * 4096, t);
        }
        bar_lds();
    }
    float lsum = (lsum4[0] + lsum4[1]) + (lsum4[2] + lsum4[3]);
    lsum += __shfl_xor(lsum, 16);
    lsum += __shfl_xor(lsum, 32);
    const float c2 = M20LOG2E - __log2f(lsum);   // exp2(fma(s,LOG2E_O8,c2)) = normalized w

    // ------------- sweep 2: weights write + PV ----------------------
    f32x4 oacc[4];
#pragma unroll
    for (int dt = 0; dt < 4; ++dt) oacc[dt] = (f32x4){0.f, 0.f, 0.f, 0.f};

    f32x4 vreg[2];
    kload(kreg, Kg, t);
    vload(vreg, Vg, t);
    kwrite(lkb, kreg, t);          // all waves passed sweep1's final barrier
    vtwrite(lv, vreg, t);          // V0
    kload(kreg, Kg + 4096, t);
    vload(vreg, Vg + 4096, t);
    bar_lds();

    for (int kt = 0; kt <= b; ++kt) {
        const short* lk = lkb + (kt & 1) * 4096;
        const bool blive = (kt * 64 <= qwbase);    // wave-uniform: tile has live cols

        if (blive) {
            // ---- compute all 4 kc sub-tiles; P -> per-wave LDS (bf16) ----
#pragma unroll
            for (int kc = 0; kc < 4; ++kc) {
                int kgb = kt * 64 + 16 * kc;
                bool live = (kgb <= qwbase);       // wave-uniform
                f32x4 wv;
                if (live) {
                    bf16x8 kb0 = frag_ld(lk, 16 * kc + l15, 0 + l4);
                    bf16x8 kb1 = frag_ld(lk, 16 * kc + l15, 4 + l4);
                    f32x4 acc = {0.f, 0.f, 0.f, 0.f};
                    acc = __builtin_amdgcn_mfma_f32_16x16x32_bf16(kb0, qa0, acc, 0, 0, 0);
                    acc = __builtin_amdgcn_mfma_f32_16x16x32_bf16(kb1, qa1, acc, 0, 0, 0);
                    if (kgb != qwbase) {           // interior: no per-element mask
#pragma unroll
                        for (int r = 0; r < 4; ++r)
                            wv[r] = exp2f(fmaf(acc[r], LOG2E_O8, c2));
                    } else {
#pragma unroll
                        for (int r = 0; r < 4; ++r) {
                            int kg = kgb + 4 * l4 + r;
                            wv[r] = (kg <= qg) ? exp2f(fmaf(acc[r], LOG2E_O8, c2)) : 0.0f;
                        }
                    }
                } else {
                    wv = (f32x4){0.f, 0.f, 0.f, 0.f};
                }
                uint2v pk;
                pk.x = cvt_pk(wv[0], wv[1]);
                pk.y = cvt_pk(wv[2], wv[3]);
                int s8 = 2 * kc + (l4 >> 1);
                *(uint2v*)((char*)lp + 16 * swz(l15, s8) + (l4 & 1) * 8) = pk;
            }
            // ---- W store: LDS-transposed, 16 lanes per row -> 256B runs ----
#pragma unroll
            for (int j = 0; j < 4; ++j) {
                int rr = j * 4 + l4;               // tile row 0..15
                uint2v pk = *(const uint2v*)((char*)lp + 16 * swz(rr, l15 >> 1) + (l15 & 1) * 8);
                f32x4 wf;
                wf.x = __uint_as_float(pk.x << 16);
                wf.y = __uint_as_float(pk.x & 0xffff0000u);
                wf.z = __uint_as_float(pk.y << 16);
                wf.w = __uint_as_float(pk.y & 0xffff0000u);
                nt_store4(Wh + (size_t)(qwbase + rr) * S_ + kt * 64 + 4 * l15, wf);
            }
        }

        // stage next K while PV runs (lkb[nxt] safe: sealed by prev bar pair)
        if (kt < b) {
            kwrite(lkb + ((kt + 1) & 1) * 4096, kreg, t);
            if (kt + 1 < b) kload(kreg, Kg + (size_t)(kt + 2) * 4096, t);
        }

        if (blive) {
            // ---- PV: O[16q x 64d] += P(16x64) * Vt (single buf, V=kt) ----
#pragma unroll
            for (int kchunk = 0; kchunk < 2; ++kchunk) {
                bf16x8 pa = frag_ld(lp, l15, kchunk * 4 + l4);
#pragma unroll
                for (int dt = 0; dt < 4; ++dt) {
                    bf16x8 vb = frag_ld(lv, 16 * dt + l15, kchunk * 4 + l4);
                    oacc[dt] = __builtin_amdgcn_mfma_f32_16x16x32_bf16(pa, vb, oacc[dt], 0, 0, 0);
                }
            }
        }
        bar_lds();                                 // all PV(kt) reads of lv done
        if (kt < b) {
            vtwrite(lv, vreg, t);                  // V(kt+1) into single buf
            if (kt + 1 < b) vload(vreg, Vg + (size_t)(kt + 2) * 4096, t);
        }
        bar_lds();                                 // vtwrite complete before PV(kt+1)
    }

    // -------- write O --------
#pragma unroll
    for (int dt = 0; dt < 4; ++dt)
#pragma unroll
        for (int r = 0; r < 4; ++r)
            Oh[(size_t)(qwbase + 4 * l4 + r) * D_ + 16 * dt + l15] = oacc[dt][r];
}

extern "C" void kernel_launch(void* const* d_in, const int* in_sizes, int n_in,
                              void* d_out, int out_size, void* d_ws, size_t ws_size,
                              hipStream_t stream) {
    const float* q = (const float*)d_in[0];
    const float* k = (const float*)d_in[1];
    const float* v = (const float*)d_in[2];
    float* out = (float*)d_out;
    attn_kernel<<<dim3(1024), dim3(THREADS), 0, stream>>>(q, k, v, out);
}

// Round 12
// 240.680 us; speedup vs baseline: 1.3620x; 1.0031x over previous
//
#include <hip/hip_runtime.h>
#include <hip/hip_bf16.h>

#define B_ 4
#define H_ 16
#define S_ 2048
#define D_ 64
#define THREADS 512

typedef float  f32x4  __attribute__((ext_vector_type(4)));
typedef short  bf16x8 __attribute__((ext_vector_type(8)));
typedef unsigned uint2v __attribute__((ext_vector_type(2)));

#define LOG2E_O8  0.18033688011112042f   // log2(e)/8
#define M20LOG2E -28.853900817779268f    // -20*log2(e)

// packed f32x2 -> bf16x2 (RNE), single VOP3 instr
__device__ __forceinline__ unsigned cvt_pk(float lo, float hi) {
    unsigned r;
    asm("v_cvt_pk_bf16_f32 %0, %1, %2" : "=v"(r) : "v"(lo), "v"(hi));
    return r;
}

__device__ __forceinline__ void nt_store4(float* p, f32x4 v) {
    __builtin_nontemporal_store(v, (f32x4*)p);
}

// LDS-only barrier (no vmcnt drain): in-flight global stores/loads float across.
__device__ __forceinline__ void bar_lds() {
    asm volatile("s_waitcnt lgkmcnt(0)\n\ts_barrier" ::: "memory");
}

// swizzled 16B-slot index for a [rows][64 bf16] LDS tile (8 slots/row)
__device__ __forceinline__ int swz(int row, int s8) {
    return row * 8 + (s8 ^ ((row & 7) ^ ((row >> 3) & 7)));
}

__device__ __forceinline__ bf16x8 frag_ld(const short* lds, int row, int s8) {
    return *(const bf16x8*)((const char*)lds + 16 * swz(row, s8));
}

// ---- K-tile (64x64 f32) reg staging: 2 f32x4 per thread (512 threads) ----
__device__ __forceinline__ void kload(f32x4 (&r)[2], const float* __restrict__ g, int t) {
    r[0] = *(const f32x4*)(g + 4 * t);
    r[1] = *(const f32x4*)(g + 4 * (t + THREADS));
}
__device__ __forceinline__ void kwrite(short* lds, const f32x4 (&r)[2], int t) {
#pragma unroll
    for (int i = 0; i < 2; ++i) {
        int f = t + i * THREADS;
        int row = f >> 4, c4 = f & 15;
        uint2v h;
        h.x = cvt_pk(r[i].x, r[i].y);
        h.y = cvt_pk(r[i].z, r[i].w);
        *(uint2v*)((char*)lds + 16 * swz(row, c4 >> 1) + (c4 & 1) * 8) = h;
    }
}
// ---- V-tile (64x64) reg staging for TRANSPOSED store ----
__device__ __forceinline__ void vload(f32x4 (&r)[2], const float* __restrict__ g, int t) {
    int k0 = (t >> 4) * 2, d0 = (t & 15) * 4;
    r[0] = *(const f32x4*)(g + k0 * 64 + d0);
    r[1] = *(const f32x4*)(g + (k0 + 1) * 64 + d0);
}
__device__ __forceinline__ void vtwrite(short* lds, const f32x4 (&r)[2], int t) {
    int k0 = (t >> 4) * 2, d0 = (t & 15) * 4;
#pragma unroll
    for (int j = 0; j < 4; ++j) {
        unsigned pk = cvt_pk(r[0][j], r[1][j]);    // (k0 low, k0+1 high)
        int row = d0 + j;                          // d -> Vt row
        *(unsigned*)((char*)lds + 16 * swz(row, k0 >> 3) + (k0 & 7) * 2) = pk;
    }
}

__global__ __launch_bounds__(THREADS)
void attn_kernel(const float* __restrict__ Q, const float* __restrict__ K,
                 const float* __restrict__ V, float* __restrict__ Out) {
    const int t    = threadIdx.x;
    const int lane = t & 63;
    const int w    = t >> 6;        // wave 0..7
    const int wg   = w & 3;         // wave within 4-wave group
    const int grp  = w >> 2;        // 0 -> subtile a, 1 -> subtile b
    const int l15  = lane & 15;
    const int l4   = lane >> 4;     // 0..3

    // XCD-chunked head mapping; block = complementary 64-row subtile pair (a, 31-a)
    const int bid = blockIdx.x;
    const int u   = bid >> 3;                 // 0..127 within XCD
    const int bh  = (bid & 7) * 8 + (u >> 4); // head (8 per XCD)
    const int a   = u & 15;                   // pair index
    const int b   = 31 - a;
    const int q0  = (grp ? b : a) * 64;       // this wave-group's subtile base

    const float* Kg = K + (size_t)bh * S_ * D_;
    const float* Vg = V + (size_t)bh * S_ * D_;
    float* Wh = Out + (size_t)B_ * H_ * S_ * D_ + (size_t)bh * S_ * (size_t)S_;
    float* Oh = Out + (size_t)bh * S_ * D_;

    __shared__ char pool[49152];
    short* lkb = (short*)pool;                        // K dbuf 2x8KB
    short* lvb = (short*)(pool + 16384);              // Vt dbuf 2x8KB
    short* lp  = (short*)(pool + 32768) + w * 1024;   // per-wave P tile 2KB

    // -------- Q fragments straight from global --------
    bf16x8 qa0, qa1;
    {
        const float* qrow = Q + ((size_t)bh * S_ + q0 + 16 * wg + l15) * D_;
        f32x4 a0 = *(const f32x4*)(qrow + 8 * l4);
        f32x4 a1 = *(const f32x4*)(qrow + 8 * l4 + 4);
        f32x4 b0 = *(const f32x4*)(qrow + 32 + 8 * l4);
        f32x4 b1 = *(const f32x4*)(qrow + 32 + 8 * l4 + 4);
        union { bf16x8 v; unsigned u[4]; } q0u, q1u;
        q0u.u[0] = cvt_pk(a0.x, a0.y); q0u.u[1] = cvt_pk(a0.z, a0.w);
        q0u.u[2] = cvt_pk(a1.x, a1.y); q0u.u[3] = cvt_pk(a1.z, a1.w);
        q1u.u[0] = cvt_pk(b0.x, b0.y); q1u.u[1] = cvt_pk(b0.z, b0.w);
        q1u.u[2] = cvt_pk(b1.x, b1.y); q1u.u[3] = cvt_pk(b1.z, b1.w);
        qa0 = q0u.v; qa1 = q1u.v;
    }

    const int qwbase = q0 + 16 * wg;               // wave's first q row
    const int qg     = qwbase + l15;               // lane's q row (S^T layout)

    // ---------------- sweep 1: row sums + PACED zero-fill ----------------------
    // swapped QK^T: mfma(K,Q) -> lane holds S[q=l15][k=kgb+4*l4+r]
    f32x4 kreg[2];
    kload(kreg, Kg, t);
    kwrite(lkb, kreg, t);
    kload(kreg, Kg + 4096, t);
    bar_lds();

    // fill state: 31 dead 64x64 tiles (const per block) as 62 half-tiles
    int fcur = 0;
    const int fquota = (62 + b) / (b + 1);        // ceil(62/(b+1)) in {2,3,4}
    const f32x4 z4 = {0.f, 0.f, 0.f, 0.f};
    const int frow = t >> 4, fcol = 4 * (t & 15);

    f32x4 lsum4 = {0.f, 0.f, 0.f, 0.f};           // 4 independent chains
    for (int kt = 0; kt <= b; ++kt) {
        const short* lk = lkb + (kt & 1) * 4096;
        if (kt * 64 <= qwbase) {
#pragma unroll
            for (int kc = 0; kc < 4; ++kc) {
                int kgb = kt * 64 + 16 * kc;
                if (kgb > qwbase) break;            // wave-uniform (dead)
                bf16x8 kb0 = frag_ld(lk, 16 * kc + l15, 0 + l4);
                bf16x8 kb1 = frag_ld(lk, 16 * kc + l15, 4 + l4);
                f32x4 acc = {0.f, 0.f, 0.f, 0.f};
                acc = __builtin_amdgcn_mfma_f32_16x16x32_bf16(kb0, qa0, acc, 0, 0, 0);
                acc = __builtin_amdgcn_mfma_f32_16x16x32_bf16(kb1, qa1, acc, 0, 0, 0);
                if (kgb != qwbase) {                // interior: all 16 live
#pragma unroll
                    for (int r = 0; r < 4; ++r)
                        lsum4[r] += exp2f(fmaf(acc[r], LOG2E_O8, M20LOG2E));
                } else {                            // diagonal-partial sub-tile
#pragma unroll
                    for (int r = 0; r < 4; ++r) {
                        int kg = kgb + 4 * l4 + r;
                        if (kg <= qg) lsum4[r] += exp2f(fmaf(acc[r], LOG2E_O8, M20LOG2E));
                    }
                }
            }
        }
        // paced zero-fill: fquota half-tiles (8KB each) per iteration
        for (int f = 0; f < fquota; ++f) {
            if (fcur >= 62) break;
            int zt = fcur >> 1, half = fcur & 1;
            int rowb, ktile;
            if (zt < b) { rowb = 64 * a; ktile = a + 1 + zt; }   // tile-a dead cols
            else        { rowb = 64 * b; ktile = zt + 1; }       // tile-b dead cols
            nt_store4(Wh + (size_t)(rowb + 32 * half + frow) * S_ + 64 * ktile + fcol, z4);
            ++fcur;
        }
        if (kt < b) {
            kwrite(lkb + ((kt + 1) & 1) * 4096, kreg, t);
            if (kt + 1 < b) kload(kreg, Kg + (size_t)(kt + 2) * 4096, t);
        }
        bar_lds();
    }
    float lsum = (lsum4[0] + lsum4[1]) + (lsum4[2] + lsum4[3]);
    lsum += __shfl_xor(lsum, 16);
    lsum += __shfl_xor(lsum, 32);
    const float c2 = M20LOG2E - __log2f(lsum);   // exp2(fma(s,LOG2E_O8,c2)) = normalized w

    // ------------- sweep 2: weights write + PV (dbuf K and V, 1 bar/tile) ------
    f32x4 oacc[4];
#pragma unroll
    for (int dt = 0; dt < 4; ++dt) oacc[dt] = (f32x4){0.f, 0.f, 0.f, 0.f};

    f32x4 vreg[2];
    kload(kreg, Kg, t);
    vload(vreg, Vg, t);
    kwrite(lkb, kreg, t);          // all waves passed sweep1's final barrier
    vtwrite(lvb, vreg, t);         // V0 -> buf0
    kload(kreg, Kg + 4096, t);
    vload(vreg, Vg + 4096, t);
    bar_lds();

    for (int kt = 0; kt <= b; ++kt) {
        const short* lk = lkb + (kt & 1) * 4096;
        const short* lv = lvb + (kt & 1) * 4096;
        const bool blive = (kt * 64 <= qwbase);    // wave-uniform: tile has live cols

        if (blive) {
            // ---- compute all 4 kc sub-tiles; P -> per-wave LDS (bf16) ----
#pragma unroll
            for (int kc = 0; kc < 4; ++kc) {
                int kgb = kt * 64 + 16 * kc;
                bool live = (kgb <= qwbase);       // wave-uniform
                f32x4 wv;
                if (live) {
                    bf16x8 kb0 = frag_ld(lk, 16 * kc + l15, 0 + l4);
                    bf16x8 kb1 = frag_ld(lk, 16 * kc + l15, 4 + l4);
                    f32x4 acc = {0.f, 0.f, 0.f, 0.f};
                    acc = __builtin_amdgcn_mfma_f32_16x16x32_bf16(kb0, qa0, acc, 0, 0, 0);
                    acc = __builtin_amdgcn_mfma_f32_16x16x32_bf16(kb1, qa1, acc, 0, 0, 0);
                    if (kgb != qwbase) {           // interior: no per-element mask
#pragma unroll
                        for (int r = 0; r < 4; ++r)
                            wv[r] = exp2f(fmaf(acc[r], LOG2E_O8, c2));
                    } else {
#pragma unroll
                        for (int r = 0; r < 4; ++r) {
                            int kg = kgb + 4 * l4 + r;
                            wv[r] = (kg <= qg) ? exp2f(fmaf(acc[r], LOG2E_O8, c2)) : 0.0f;
                        }
                    }
                } else {
                    wv = (f32x4){0.f, 0.f, 0.f, 0.f};
                }
                uint2v pk;
                pk.x = cvt_pk(wv[0], wv[1]);
                pk.y = cvt_pk(wv[2], wv[3]);
                int s8 = 2 * kc + (l4 >> 1);
                *(uint2v*)((char*)lp + 16 * swz(l15, s8) + (l4 & 1) * 8) = pk;
            }
            // ---- W store: LDS-transposed, 16 lanes per row -> 256B runs ----
#pragma unroll
            for (int j = 0; j < 4; ++j) {
                int rr = j * 4 + l4;               // tile row 0..15
                uint2v pk = *(const uint2v*)((char*)lp + 16 * swz(rr, l15 >> 1) + (l15 & 1) * 8);
                f32x4 wf;
                wf.x = __uint_as_float(pk.x << 16);
                wf.y = __uint_as_float(pk.x & 0xffff0000u);
                wf.z = __uint_as_float(pk.y << 16);
                wf.w = __uint_as_float(pk.y & 0xffff0000u);
                nt_store4(Wh + (size_t)(qwbase + rr) * S_ + kt * 64 + 4 * l15, wf);
            }
        }

        // stage next K/V into the other buffers (sealed by previous barrier)
        if (kt < b) {
            kwrite(lkb + ((kt + 1) & 1) * 4096, kreg, t);
            vtwrite(lvb + ((kt + 1) & 1) * 4096, vreg, t);
            if (kt + 1 < b) {
                kload(kreg, Kg + (size_t)(kt + 2) * 4096, t);
                vload(vreg, Vg + (size_t)(kt + 2) * 4096, t);
            }
        }

        if (blive) {
            // ---- PV: O[16q x 64d] += P(16x64) * Vt ----
#pragma unroll
            for (int kchunk = 0; kchunk < 2; ++kchunk) {
                bf16x8 pa = frag_ld(lp, l15, kchunk * 4 + l4);
#pragma unroll
                for (int dt = 0; dt < 4; ++dt) {
                    bf16x8 vb = frag_ld(lv, 16 * dt + l15, kchunk * 4 + l4);
                    oacc[dt] = __builtin_amdgcn_mfma_f32_16x16x32_bf16(pa, vb, oacc[dt], 0, 0, 0);
                }
            }
        }
        bar_lds();                                 // seals this tile's LDS reads+writes
    }

    // -------- write O --------
#pragma unroll
    for (int dt = 0; dt < 4; ++dt)
#pragma unroll
        for (int r = 0; r < 4; ++r)
            Oh[(size_t)(qwbase + 4 * l4 + r) * D_ + 16 * dt + l15] = oacc[dt][r];
}

extern "C" void kernel_launch(void* const* d_in, const int* in_sizes, int n_in,
                              void* d_out, int out_size, void* d_ws, size_t ws_size,
                              hipStream_t stream) {
    const float* q = (const float*)d_in[0];
    const float* k = (const float*)d_in[1];
    const float* v = (const float*)d_in[2];
    float* out = (float*)d_out;
    attn_kernel<<<dim3(1024), dim3(THREADS), 0, stream>>>(q, k, v, out);
}

// Round 13
// 240.324 us; speedup vs baseline: 1.3640x; 1.0015x over previous
//
#include <hip/hip_runtime.h>
#include <hip/hip_bf16.h>

#define B_ 4
#define H_ 16
#define S_ 2048
#define D_ 64
#define THREADS 512

typedef float  f32x4  __attribute__((ext_vector_type(4)));
typedef short  bf16x8 __attribute__((ext_vector_type(8)));
typedef unsigned uint2v __attribute__((ext_vector_type(2)));

#define LOG2E_O8  0.18033688011112042f   // log2(e)/8
#define M20LOG2E -28.853900817779268f    // -20*log2(e)

// packed f32x2 -> bf16x2 (RNE), single VOP3 instr
__device__ __forceinline__ unsigned cvt_pk(float lo, float hi) {
    unsigned r;
    asm("v_cvt_pk_bf16_f32 %0, %1, %2" : "=v"(r) : "v"(lo), "v"(hi));
    return r;
}

__device__ __forceinline__ void nt_store4(float* p, f32x4 v) {
    __builtin_nontemporal_store(v, (f32x4*)p);
}

// LDS-only barrier (no vmcnt drain): in-flight global stores/loads float across.
__device__ __forceinline__ void bar_lds() {
    asm volatile("s_waitcnt lgkmcnt(0)\n\ts_barrier" ::: "memory");
}

// swizzled 16B-slot index for a [rows][64 bf16] LDS tile (8 slots/row)
__device__ __forceinline__ int swz(int row, int s8) {
    return row * 8 + (s8 ^ ((row & 7) ^ ((row >> 3) & 7)));
}

__device__ __forceinline__ bf16x8 frag_ld(const short* lds, int row, int s8) {
    return *(const bf16x8*)((const char*)lds + 16 * swz(row, s8));
}

// ---- K-tile (64x64 f32) reg staging: 2 f32x4 per thread (512 threads) ----
__device__ __forceinline__ void kload(f32x4 (&r)[2], const float* __restrict__ g, int t) {
    r[0] = *(const f32x4*)(g + 4 * t);
    r[1] = *(const f32x4*)(g + 4 * (t + THREADS));
}
__device__ __forceinline__ void kwrite(short* lds, const f32x4 (&r)[2], int t) {
#pragma unroll
    for (int i = 0; i < 2; ++i) {
        int f = t + i * THREADS;
        int row = f >> 4, c4 = f & 15;
        uint2v h;
        h.x = cvt_pk(r[i].x, r[i].y);
        h.y = cvt_pk(r[i].z, r[i].w);
        *(uint2v*)((char*)lds + 16 * swz(row, c4 >> 1) + (c4 & 1) * 8) = h;
    }
}
// ---- V-tile (64x64) reg staging for TRANSPOSED store ----
__device__ __forceinline__ void vload(f32x4 (&r)[2], const float* __restrict__ g, int t) {
    int k0 = (t >> 4) * 2, d0 = (t & 15) * 4;
    r[0] = *(const f32x4*)(g + k0 * 64 + d0);
    r[1] = *(const f32x4*)(g + (k0 + 1) * 64 + d0);
}
__device__ __forceinline__ void vtwrite(short* lds, const f32x4 (&r)[2], int t) {
    int k0 = (t >> 4) * 2, d0 = (t & 15) * 4;
#pragma unroll
    for (int j = 0; j < 4; ++j) {
        unsigned pk = cvt_pk(r[0][j], r[1][j]);    // (k0 low, k0+1 high)
        int row = d0 + j;                          // d -> Vt row
        *(unsigned*)((char*)lds + 16 * swz(row, k0 >> 3) + (k0 & 7) * 2) = pk;
    }
}

__global__ __launch_bounds__(THREADS, 4)   // cap VGPR at 128 -> 2 blocks/CU
void attn_kernel(const float* __restrict__ Q, const float* __restrict__ K,
                 const float* __restrict__ V, float* __restrict__ Out) {
    const int t    = threadIdx.x;
    const int lane = t & 63;
    const int w    = t >> 6;        // wave 0..7
    const int wg   = w & 3;         // wave within 4-wave group
    const int grp  = w >> 2;        // 0 -> subtile a, 1 -> subtile b
    const int l15  = lane & 15;
    const int l4   = lane >> 4;     // 0..3

    // XCD-chunked head mapping; block = complementary 64-row subtile pair (a, 31-a)
    const int bid = blockIdx.x;
    const int u   = bid >> 3;                 // 0..127 within XCD
    const int bh  = (bid & 7) * 8 + (u >> 4); // head (8 per XCD)
    const int a   = u & 15;                   // pair index
    const int b   = 31 - a;
    const int q0  = (grp ? b : a) * 64;       // this wave-group's subtile base

    const float* Kg = K + (size_t)bh * S_ * D_;
    const float* Vg = V + (size_t)bh * S_ * D_;
    float* Wh = Out + (size_t)B_ * H_ * S_ * D_ + (size_t)bh * S_ * (size_t)S_;
    float* Oh = Out + (size_t)bh * S_ * D_;

    __shared__ char pool[49152];
    short* lkb = (short*)pool;                        // K dbuf 2x8KB
    short* lvb = (short*)(pool + 16384);              // Vt dbuf 2x8KB
    short* lp  = (short*)(pool + 32768) + w * 1024;   // per-wave P tile 2KB

    // -------- Q fragments straight from global --------
    bf16x8 qa0, qa1;
    {
        const float* qrow = Q + ((size_t)bh * S_ + q0 + 16 * wg + l15) * D_;
        f32x4 a0 = *(const f32x4*)(qrow + 8 * l4);
        f32x4 a1 = *(const f32x4*)(qrow + 8 * l4 + 4);
        f32x4 b0 = *(const f32x4*)(qrow + 32 + 8 * l4);
        f32x4 b1 = *(const f32x4*)(qrow + 32 + 8 * l4 + 4);
        union { bf16x8 v; unsigned u[4]; } q0u, q1u;
        q0u.u[0] = cvt_pk(a0.x, a0.y); q0u.u[1] = cvt_pk(a0.z, a0.w);
        q0u.u[2] = cvt_pk(a1.x, a1.y); q0u.u[3] = cvt_pk(a1.z, a1.w);
        q1u.u[0] = cvt_pk(b0.x, b0.y); q1u.u[1] = cvt_pk(b0.z, b0.w);
        q1u.u[2] = cvt_pk(b1.x, b1.y); q1u.u[3] = cvt_pk(b1.z, b1.w);
        qa0 = q0u.v; qa1 = q1u.v;
    }

    const int qwbase = q0 + 16 * wg;               // wave's first q row
    const int qg     = qwbase + l15;               // lane's q row (S^T layout)

    // ---------------- sweep 1: row sums + PACED zero-fill ----------------------
    // swapped QK^T: mfma(K,Q) -> lane holds S[q=l15][k=kgb+4*l4+r]
    f32x4 kreg[2];
    kload(kreg, Kg, t);
    kwrite(lkb, kreg, t);
    kload(kreg, Kg + 4096, t);
    bar_lds();

    // fill state: 31 dead 64x64 tiles (const per block) as 62 half-tiles
    int fcur = 0;
    const int fquota = (62 + b) / (b + 1);        // ceil(62/(b+1)) in {2,3,4}
    const f32x4 z4 = {0.f, 0.f, 0.f, 0.f};
    const int frow = t >> 4, fcol = 4 * (t & 15);

    f32x4 lsum4 = {0.f, 0.f, 0.f, 0.f};           // 4 independent chains
    for (int kt = 0; kt <= b; ++kt) {
        const short* lk = lkb + (kt & 1) * 4096;
        if (kt * 64 <= qwbase) {
#pragma unroll
            for (int kc = 0; kc < 4; ++kc) {
                int kgb = kt * 64 + 16 * kc;
                if (kgb > qwbase) break;            // wave-uniform (dead)
                bf16x8 kb0 = frag_ld(lk, 16 * kc + l15, 0 + l4);
                bf16x8 kb1 = frag_ld(lk, 16 * kc + l15, 4 + l4);
                f32x4 acc = {0.f, 0.f, 0.f, 0.f};
                acc = __builtin_amdgcn_mfma_f32_16x16x32_bf16(kb0, qa0, acc, 0, 0, 0);
                acc = __builtin_amdgcn_mfma_f32_16x16x32_bf16(kb1, qa1, acc, 0, 0, 0);
                if (kgb != qwbase) {                // interior: all 16 live
#pragma unroll
                    for (int r = 0; r < 4; ++r)
                        lsum4[r] += exp2f(fmaf(acc[r], LOG2E_O8, M20LOG2E));
                } else {                            // diagonal-partial sub-tile
#pragma unroll
                    for (int r = 0; r < 4; ++r) {
                        int kg = kgb + 4 * l4 + r;
                        if (kg <= qg) lsum4[r] += exp2f(fmaf(acc[r], LOG2E_O8, M20LOG2E));
                    }
                }
            }
        }
        // paced zero-fill: fquota half-tiles (8KB each) per iteration
        for (int f = 0; f < fquota; ++f) {
            if (fcur >= 62) break;
            int zt = fcur >> 1, half = fcur & 1;
            int rowb, ktile;
            if (zt < b) { rowb = 64 * a; ktile = a + 1 + zt; }   // tile-a dead cols
            else        { rowb = 64 * b; ktile = zt + 1; }       // tile-b dead cols
            nt_store4(Wh + (size_t)(rowb + 32 * half + frow) * S_ + 64 * ktile + fcol, z4);
            ++fcur;
        }
        if (kt < b) {
            kwrite(lkb + ((kt + 1) & 1) * 4096, kreg, t);
            if (kt + 1 < b) kload(kreg, Kg + (size_t)(kt + 2) * 4096, t);
        }
        bar_lds();
    }
    float lsum = (lsum4[0] + lsum4[1]) + (lsum4[2] + lsum4[3]);
    lsum += __shfl_xor(lsum, 16);
    lsum += __shfl_xor(lsum, 32);
    const float c2 = M20LOG2E - __log2f(lsum);   // exp2(fma(s,LOG2E_O8,c2)) = normalized w

    // ------------- sweep 2: weights write + PV (dbuf K and V, 1 bar/tile) ------
    f32x4 oacc[4];
#pragma unroll
    for (int dt = 0; dt < 4; ++dt) oacc[dt] = (f32x4){0.f, 0.f, 0.f, 0.f};

    f32x4 vreg[2];
    kload(kreg, Kg, t);
    vload(vreg, Vg, t);
    kwrite(lkb, kreg, t);          // all waves passed sweep1's final barrier
    vtwrite(lvb, vreg, t);         // V0 -> buf0
    kload(kreg, Kg + 4096, t);
    vload(vreg, Vg + 4096, t);
    bar_lds();

    for (int kt = 0; kt <= b; ++kt) {
        const short* lk = lkb + (kt & 1) * 4096;
        const short* lv = lvb + (kt & 1) * 4096;
        const bool blive = (kt * 64 <= qwbase);    // wave-uniform: tile has live cols

        if (blive) {
            // ---- compute all 4 kc sub-tiles; P -> per-wave LDS (bf16) ----
#pragma unroll
            for (int kc = 0; kc < 4; ++kc) {
                int kgb = kt * 64 + 16 * kc;
                bool live = (kgb <= qwbase);       // wave-uniform
                f32x4 wv;
                if (live) {
                    bf16x8 kb0 = frag_ld(lk, 16 * kc + l15, 0 + l4);
                    bf16x8 kb1 = frag_ld(lk, 16 * kc + l15, 4 + l4);
                    f32x4 acc = {0.f, 0.f, 0.f, 0.f};
                    acc = __builtin_amdgcn_mfma_f32_16x16x32_bf16(kb0, qa0, acc, 0, 0, 0);
                    acc = __builtin_amdgcn_mfma_f32_16x16x32_bf16(kb1, qa1, acc, 0, 0, 0);
                    if (kgb != qwbase) {           // interior: no per-element mask
#pragma unroll
                        for (int r = 0; r < 4; ++r)
                            wv[r] = exp2f(fmaf(acc[r], LOG2E_O8, c2));
                    } else {
#pragma unroll
                        for (int r = 0; r < 4; ++r) {
                            int kg = kgb + 4 * l4 + r;
                            wv[r] = (kg <= qg) ? exp2f(fmaf(acc[r], LOG2E_O8, c2)) : 0.0f;
                        }
                    }
                } else {
                    wv = (f32x4){0.f, 0.f, 0.f, 0.f};
                }
                uint2v pk;
                pk.x = cvt_pk(wv[0], wv[1]);
                pk.y = cvt_pk(wv[2], wv[3]);
                int s8 = 2 * kc + (l4 >> 1);
                *(uint2v*)((char*)lp + 16 * swz(l15, s8) + (l4 & 1) * 8) = pk;
            }
            // ---- W store: LDS-transposed, 16 lanes per row -> 256B runs ----
#pragma unroll
            for (int j = 0; j < 4; ++j) {
                int rr = j * 4 + l4;               // tile row 0..15
                uint2v pk = *(const uint2v*)((char*)lp + 16 * swz(rr, l15 >> 1) + (l15 & 1) * 8);
                f32x4 wf;
                wf.x = __uint_as_float(pk.x << 16);
                wf.y = __uint_as_float(pk.x & 0xffff0000u);
                wf.z = __uint_as_float(pk.y << 16);
                wf.w = __uint_as_float(pk.y & 0xffff0000u);
                nt_store4(Wh + (size_t)(qwbase + rr) * S_ + kt * 64 + 4 * l15, wf);
            }
        }

        // stage next K/V into the other buffers (sealed by previous barrier)
        if (kt < b) {
            kwrite(lkb + ((kt + 1) & 1) * 4096, kreg, t);
            vtwrite(lvb + ((kt + 1) & 1) * 4096, vreg, t);
            if (kt + 1 < b) {
                kload(kreg, Kg + (size_t)(kt + 2) * 4096, t);
                vload(vreg, Vg + (size_t)(kt + 2) * 4096, t);
            }
        }

        if (blive) {
            // ---- PV: O[16q x 64d] += P(16x64) * Vt ----
#pragma unroll
            for (int kchunk = 0; kchunk < 2; ++kchunk) {
                bf16x8 pa = frag_ld(lp, l15, kchunk * 4 + l4);
#pragma unroll
                for (int dt = 0; dt < 4; ++dt) {
                    bf16x8 vb = frag_ld(lv, 16 * dt + l15, kchunk * 4 + l4);
                    oacc[dt] = __builtin_amdgcn_mfma_f32_16x16x32_bf16(pa, vb, oacc[dt], 0, 0, 0);
                }
            }
        }
        bar_lds();                                 // seals this tile's LDS reads+writes
    }

    // -------- write O --------
#pragma unroll
    for (int dt = 0; dt < 4; ++dt)
#pragma unroll
        for (int r = 0; r < 4; ++r)
            Oh[(size_t)(qwbase + 4 * l4 + r) * D_ + 16 * dt + l15] = oacc[dt][r];
}

extern "C" void kernel_launch(void* const* d_in, const int* in_sizes, int n_in,
                              void* d_out, int out_size, void* d_ws, size_t ws_size,
                              hipStream_t stream) {
    const float* q = (const float*)d_in[0];
    const float* k = (const float*)d_in[1];
    const float* v = (const float*)d_in[2];
    float* out = (float*)d_out;
    attn_kernel<<<dim3(1024), dim3(THREADS), 0, stream>>>(q, k, v, out);
}